// Round 7
// baseline (83.467 us; speedup 1.0000x reference)
//
#include <hip/hip_runtime.h>
#include <math.h>

#define NEG_INF (-1e30f)

typedef __attribute__((ext_vector_type(8))) short s16x8;   // 8 bf16 = 4 VGPRs (MFMA A/B frag)
typedef __attribute__((ext_vector_type(4))) float f32x4;   // MFMA C/D frag

// RNE float->bf16 pair pack (lo -> low short, hi -> high short)
__device__ __forceinline__ unsigned int pack_bf16(float lo, float hi) {
    unsigned int ul = __float_as_uint(lo);
    ul += 0x7FFFu + ((ul >> 16) & 1u);
    unsigned int uh = __float_as_uint(hi);
    uh += 0x7FFFu + ((uh >> 16) & 1u);
    return (ul >> 16) | (uh & 0xFFFF0000u);
}

// ---- Kernel 1: one-time transpose + fp32-normalize + bf16 pack ----
// Grid 128: blocks 0-63 -> student, 64-127 -> teacher; 64 positions each.
// Output layout [n][64] bf16: one position = 128 B; an MFMA fragment is a
// contiguous 16-B slice of it -> main kernel needs no LDS. Block 0 zeroes
// the atomic accumulators (visible to K2 via stream order + kernel-end flush).
__global__ __launch_bounds__(256) void prep_kernel(
    const float* __restrict__ s, const float* __restrict__ t,
    unsigned int* __restrict__ sbf, unsigned int* __restrict__ tbf,
    float* __restrict__ accums) {
    const int b = blockIdx.x;
    const int tid = threadIdx.x;
    const int n0 = (b & 63) << 6;
    const float* __restrict__ src = (b >= 64) ? t : s;
    unsigned int* __restrict__ dst = (b >= 64) ? tbf : sbf;

    if (b == 0 && tid < 8) accums[tid] = 0.f;

    __shared__ __align__(16) float lds[64][68];
    __shared__ float red[4][64];
    __shared__ float rinv[64];

    // stage fp32 [c][pos] -> LDS [pos][c]
    {
        const int cg = tid & 15;             // c-group of 4
        const int pos4 = (tid >> 4) << 2;    // 0..60
        const int base = ((n0 >> 10) << 16) + (n0 & 1023) + pos4;
#pragma unroll
        for (int cc = 0; cc < 4; ++cc) {
            const int c = (cg << 2) + cc;
            float4 v = *(const float4*)(src + base + (c << 10));
            lds[pos4 + 0][c] = v.x;
            lds[pos4 + 1][c] = v.y;
            lds[pos4 + 2][c] = v.z;
            lds[pos4 + 3][c] = v.w;
        }
    }
    __syncthreads();

    // fp32 norms (reference semantics: normalize in fp32, then round)
    {
        const int pos = tid & 63;
        const int q = tid >> 6;
        float ssq = 0.f;
#pragma unroll
        for (int j = 0; j < 4; ++j) {
            float4 v = *(const float4*)&lds[pos][(q << 4) + (j << 2)];
            ssq = fmaf(v.x, v.x, ssq);
            ssq = fmaf(v.y, v.y, ssq);
            ssq = fmaf(v.z, v.z, ssq);
            ssq = fmaf(v.w, v.w, ssq);
        }
        red[q][pos] = ssq;
    }
    __syncthreads();
    if (tid < 64) {
        float v = red[0][tid] + red[1][tid] + red[2][tid] + red[3][tid];
        rinv[tid] = 1.f / fmaxf(sqrtf(v), 1e-12f);
    }
    __syncthreads();

    // normalize, pack to bf16, write [n][64] (coalesced uint4 stores)
    {
        const int pos = tid >> 2;            // 0..63
        const int o0 = (tid & 3) << 1;       // oct pair 0,2,4,6
        const float r = rinv[pos];
        unsigned int* drow = dst + ((n0 + pos) << 5);   // 32 words/row
#pragma unroll
        for (int oo = 0; oo < 2; ++oo) {
            const int o = o0 + oo;
            const float* lp = &lds[pos][o << 3];
            uint4 u;
            u.x = pack_bf16(lp[0] * r, lp[1] * r);
            u.y = pack_bf16(lp[2] * r, lp[3] * r);
            u.z = pack_bf16(lp[4] * r, lp[5] * r);
            u.w = pack_bf16(lp[6] * r, lp[7] * r);
            *(uint4*)(drow + (o << 2)) = u;
        }
    }
}

// ---- Kernel 2: full-row MFMA main. Grid 256 x 512 threads. ----
// Block b owns rows 16b..16b+15 and ALL 2048 cols of its image, so each
// row's softmax denominator is complete in-block: no stats matrix, no
// separate finalize dispatch. 8 waves x 256 cols; fragments read straight
// from packed [n][64] bf16 (16-B slices, L2-resident). Fixed-max softmax
// (|logit| <= ~10.3 -> exp(l-10) safe). Per-block partial -> 3 atomicAdds
// + same-cacheline ticket; winner (all 4 words on one TCC bank, FIFO)
// writes the scalar.
__global__ __launch_bounds__(512) void mainrow_kernel(
    const s16x8* __restrict__ sbf, const s16x8* __restrict__ tbf,
    const int* __restrict__ labels, float* __restrict__ accums,
    float* __restrict__ out) {

    const int b = blockIdx.x;            // 0..255
    const int i0 = b << 4;               // 16 rows
    const int img = b >> 7;              // 128 blocks per image
    const int tid = threadIdx.x;
    const int lane = tid & 63;
    const int wv = tid >> 6;             // 0..7
    const int quad = lane >> 4;
    const int col16 = lane & 15;

    // A fragments for the block's single 16-row tile (A[m=lane&15][k=quad*8+j])
    s16x8 a0 = sbf[(i0 + col16) * 8 + quad];
    s16x8 a1 = sbf[(i0 + col16) * 8 + quad + 4];

    int ig[4], labi[4];
#pragma unroll
    for (int reg = 0; reg < 4; ++reg) {
        ig[reg] = i0 + 4 * quad + reg;   // C/D row = quad*4 + reg
        labi[reg] = labels[ig[reg]];
    }

    float ssum[4] = {0.f, 0.f, 0.f, 0.f};
    float Asum[4] = {0.f, 0.f, 0.f, 0.f};
    float csum[4] = {0.f, 0.f, 0.f, 0.f};

    const int colbase = img * 2048 + (wv << 8) + col16;
#pragma unroll 4
    for (int ct = 0; ct < 16; ++ct) {
        const int col = colbase + (ct << 4);
        s16x8 b0 = tbf[col * 8 + quad];
        s16x8 b1 = tbf[col * 8 + quad + 4];
        const int lj = labels[col];
        f32x4 z = {0.f, 0.f, 0.f, 0.f};
        z = __builtin_amdgcn_mfma_f32_16x16x32_bf16(a0, b0, z, 0, 0, 0);
        z = __builtin_amdgcn_mfma_f32_16x16x32_bf16(a1, b1, z, 0, 0, 0);
#pragma unroll
        for (int reg = 0; reg < 4; ++reg) {
            float logit = z[reg] * 10.f;           // cosine / TEMPERATURE
            bool self = (col == ig[reg]);
            float e = __expf((self ? NEG_INF : logit) - 10.f);
            ssum[reg] += e;
            if (!self && lj == labi[reg]) { Asum[reg] += logit; csum[reg] += 1.f; }
        }
    }

    // reduce across the 16 col lanes (low 4 lane bits)
#pragma unroll
    for (int off = 1; off < 16; off <<= 1)
#pragma unroll
        for (int reg = 0; reg < 4; ++reg) {
            ssum[reg] += __shfl_xor(ssum[reg], off, 64);
            Asum[reg] += __shfl_xor(Asum[reg], off, 64);
            csum[reg] += __shfl_xor(csum[reg], off, 64);
        }

    __shared__ float part[3][8][16];
    if (col16 == 0) {
#pragma unroll
        for (int reg = 0; reg < 4; ++reg) {
            part[0][wv][4 * quad + reg] = ssum[reg];
            part[1][wv][4 * quad + reg] = Asum[reg];
            part[2][wv][4 * quad + reg] = csum[reg];
        }
    }
    __syncthreads();

    if (tid < 16) {   // lanes 0..15 of wave 0; shuffle partners all active
        float S = 0.f, A = 0.f, C = 0.f;
#pragma unroll
        for (int w = 0; w < 8; ++w) {
            S += part[0][w][tid];
            A += part[1][w][tid];
            C += part[2][w][tid];
        }
        float bm = 0.f, bv = 0.f, bn = 0.f;
        if (C > 0.5f) {                       // integer count; > EPS <=> >= 1
            float lse = 10.f + __logf(S);     // full-row lse, fixed max
            bm = (A - C * lse) / (C + 1e-8f);
            bv = 1.f;
            bn = (labels[i0 + tid] != 0) ? 1.f : 0.f;
        }
#pragma unroll
        for (int off = 1; off < 16; off <<= 1) {
            bm += __shfl_xor(bm, off, 64);
            bv += __shfl_xor(bv, off, 64);
            bn += __shfl_xor(bn, off, 64);
        }
        if (tid == 0) {
            atomicAdd(&accums[0], bm);
            atomicAdd(&accums[1], bv);
            atomicAdd(&accums[2], bn);
            __threadfence();
            unsigned int old = atomicAdd((unsigned int*)&accums[3], 1u);
            if (old == 255u) {   // last block; same-line atomics already drained
                float Sm = atomicAdd(&accums[0], 0.f);
                float V  = atomicAdd(&accums[1], 0.f);
                float NB = atomicAdd(&accums[2], 0.f);
                float loss = -Sm / V;
                out[0] = loss * NB / (NB + 1e-8f);
            }
        }
    }
}

extern "C" void kernel_launch(void* const* d_in, const int* in_sizes, int n_in,
                              void* d_out, int out_size, void* d_ws, size_t ws_size,
                              hipStream_t stream) {
    const float* s = (const float*)d_in[0];
    const float* t = (const float*)d_in[1];
    const int* labels = (const int*)d_in[2];
    float* out = (float*)d_out;

    char* ws = (char*)d_ws;
    float* accums = (float*)ws;                      // 32 B (zeroed by prep)
    unsigned int* sbf = (unsigned int*)(ws + 1024);  // 4096*128 B = 512 KB
    unsigned int* tbf = (unsigned int*)(ws + 1024 + 524288);

    hipLaunchKernelGGL(prep_kernel, dim3(128), dim3(256), 0, stream,
                       s, t, sbf, tbf, accums);
    hipLaunchKernelGGL(mainrow_kernel, dim3(256), dim3(512), 0, stream,
                       (const s16x8*)sbf, (const s16x8*)tbf, labels, accums, out);
}

// Round 8
// 74.225 us; speedup vs baseline: 1.1245x; 1.1245x over previous
//
#include <hip/hip_runtime.h>
#include <math.h>

#define NEG_INF (-1e30f)

typedef __attribute__((ext_vector_type(8))) short s16x8;   // 8 bf16 = 4 VGPRs (MFMA A/B frag)
typedef __attribute__((ext_vector_type(4))) float f32x4;   // MFMA C/D frag

// RNE float->bf16 pair pack (lo -> low short, hi -> high short)
__device__ __forceinline__ unsigned int pack_bf16(float lo, float hi) {
    unsigned int ul = __float_as_uint(lo);
    ul += 0x7FFFu + ((ul >> 16) & 1u);
    unsigned int uh = __float_as_uint(hi);
    uh += 0x7FFFu + ((uh >> 16) & 1u);
    return (ul >> 16) | (uh & 0xFFFF0000u);
}

// Fused kernel: block-diagonal 4096x4096 masked-softmax contrastive loss
// partials via bf16 MFMA. Grid 512 = 32 row-blocks(128) x 16 col-chunks(128)
// in-image; 2 blocks/CU (39 KB LDS). Phases: stage fp32->bf16 [pos][c] LDS
// (72-short stride: b128-aligned frags, balanced transpose writes) ->
// in-block norms from bf16 -> 16x16x32 MFMA (2 chained, K=64) -> fixed-max
// (logits<=10.2 so exp(l-10) is safe) masked-softmax partials -> stats.
// [R5 structure: measured best at 74.2us. R6 (prep-split, +1 dispatch) and
// R7 (full-row single-pass, 1 blk/CU + 256-block atomic tail) both regressed.]
__global__ __launch_bounds__(256, 2) void fused_scl_kernel(
    const float* __restrict__ s, const float* __restrict__ t,
    const int* __restrict__ labels, float4* __restrict__ stats,
    float* __restrict__ accums) {

    const int rb = blockIdx.x >> 4;          // row block of 128
    const int jc = blockIdx.x & 15;          // col chunk of 128
    const int img = rb >> 4;                 // 16 row-blocks per image
    const int i0 = rb * 128;
    const int jb = img * 2048 + jc * 128;

    const int tid = threadIdx.x;

    __shared__ __align__(16) short lds_a[128 * 72];   // [pos][c] bf16, stride 72
    __shared__ __align__(16) short lds_b[128 * 72];
    __shared__ float lds_rs[128], lds_rt[128];
    __shared__ int lds_labi[128], lds_labj[128];

    if (blockIdx.x == 0 && tid < 8) accums[tid] = 0.f;   // zero finalize accums

    if (tid < 128) lds_labi[tid] = labels[i0 + tid];
    else           lds_labj[tid - 128] = labels[jb + tid - 128];

    // ---- stage: global fp32 [c][pos] -> bf16 LDS [pos][c] ----
    {
        const int t7 = tid & 7;              // c-pair selector (write-bank spread)
        const int pos4 = (tid >> 3) << 2;    // 0..124
        const int bvi = ((i0 >> 10) << 16) + (i0 & 1023) + pos4;
        const int bvj = ((jb >> 10) << 16) + (jb & 1023) + pos4;
        unsigned int* wa = (unsigned int*)lds_a;
        unsigned int* wb = (unsigned int*)lds_b;
#pragma unroll
        for (int k = 0; k < 4; ++k) {
            const int c0 = 2 * t7 + 16 * k;
            float4 a0 = *(const float4*)(s + bvi + c0 * 1024);
            float4 a1 = *(const float4*)(s + bvi + (c0 + 1) * 1024);
            float4 b0 = *(const float4*)(t + bvj + c0 * 1024);
            float4 b1 = *(const float4*)(t + bvj + (c0 + 1) * 1024);
            const int w = t7 + 8 * k;        // word index within row (c0/2)
            wa[36 * (pos4 + 0) + w] = pack_bf16(a0.x, a1.x);
            wa[36 * (pos4 + 1) + w] = pack_bf16(a0.y, a1.y);
            wa[36 * (pos4 + 2) + w] = pack_bf16(a0.z, a1.z);
            wa[36 * (pos4 + 3) + w] = pack_bf16(a0.w, a1.w);
            wb[36 * (pos4 + 0) + w] = pack_bf16(b0.x, b1.x);
            wb[36 * (pos4 + 1) + w] = pack_bf16(b0.y, b1.y);
            wb[36 * (pos4 + 2) + w] = pack_bf16(b0.z, b1.z);
            wb[36 * (pos4 + 3) + w] = pack_bf16(b0.w, b1.w);
        }
    }
    __syncthreads();

    // ---- in-block reciprocal norms of the bf16-rounded vectors ----
    {
        const int row = tid & 127;
        const unsigned int* wr =
            (const unsigned int*)((tid < 128) ? lds_a : lds_b) + 36 * row;
        float ssq = 0.f;
#pragma unroll
        for (int i = 0; i < 8; ++i) {
            uint4 u4 = *(const uint4*)(wr + 4 * i);
            const unsigned int uu[4] = {u4.x, u4.y, u4.z, u4.w};
#pragma unroll
            for (int q = 0; q < 4; ++q) {
                float lo = __uint_as_float(uu[q] << 16);
                float hi = __uint_as_float(uu[q] & 0xFFFF0000u);
                ssq = fmaf(lo, lo, ssq);
                ssq = fmaf(hi, hi, ssq);
            }
        }
        float r = 1.f / fmaxf(sqrtf(ssq), 1e-12f);
        if (tid < 128) lds_rs[row] = r;
        else           lds_rt[row] = r;
    }
    __syncthreads();

    // ---- MFMA GEMM: per wave 32 rows x 128 cols ----
    const int lane = tid & 63;
    const int wv = tid >> 6;
    const int warow = wv << 5;
    const int quad = lane >> 4;
    const int col16 = lane & 15;

    s16x8 afr[2][2];
#pragma unroll
    for (int rt2 = 0; rt2 < 2; ++rt2) {
        const short* pa = lds_a + (warow + 16 * rt2 + col16) * 72 + 8 * quad;
        afr[rt2][0] = *(const s16x8*)pa;          // k = 0..31  (lane k = quad*8+j)
        afr[rt2][1] = *(const s16x8*)(pa + 32);   // k = 32..63
    }

    f32x4 acc[2][8];
#pragma unroll
    for (int ct = 0; ct < 8; ++ct) {
        const short* pb = lds_b + (16 * ct + col16) * 72 + 8 * quad;
        s16x8 blo = *(const s16x8*)pb;
        s16x8 bhi = *(const s16x8*)(pb + 32);
#pragma unroll
        for (int rt2 = 0; rt2 < 2; ++rt2) {
            f32x4 z = {0.f, 0.f, 0.f, 0.f};
            z = __builtin_amdgcn_mfma_f32_16x16x32_bf16(afr[rt2][0], blo, z, 0, 0, 0);
            z = __builtin_amdgcn_mfma_f32_16x16x32_bf16(afr[rt2][1], bhi, z, 0, 0, 0);
            acc[rt2][ct] = z;
        }
    }

    // ---- epilogue: scale, mask, fixed-max exp sums + numerator sums ----
    // C/D layout: col = lane&15, row = quad*4 + reg (verified m89/m91).
    float s_sum[8], A_sum[8], c_sum[8], rsi[8];
    int labi[8], ig[8];
#pragma unroll
    for (int rt2 = 0; rt2 < 2; ++rt2)
#pragma unroll
        for (int reg = 0; reg < 4; ++reg) {
            const int rr = rt2 * 4 + reg;
            const int rloc = warow + 16 * rt2 + 4 * quad + reg;
            rsi[rr] = lds_rs[rloc] * 10.f;       // fold 1/TEMPERATURE
            labi[rr] = lds_labi[rloc];
            ig[rr] = i0 + rloc;
            s_sum[rr] = 0.f; A_sum[rr] = 0.f; c_sum[rr] = 0.f;
        }

#pragma unroll
    for (int ct = 0; ct < 8; ++ct) {
        const int jg = jb + 16 * ct + col16;
        const float rtj = lds_rt[16 * ct + col16];
        const int lj = lds_labj[16 * ct + col16];
#pragma unroll
        for (int rt2 = 0; rt2 < 2; ++rt2)
#pragma unroll
            for (int reg = 0; reg < 4; ++reg) {
                const int rr = rt2 * 4 + reg;
                float logit = acc[rt2][ct][reg] * rsi[rr] * rtj;
                bool self = (jg == ig[rr]);
                float e = __expf((self ? NEG_INF : logit) - 10.f);  // <= e^0.3
                s_sum[rr] += e;
                if (!self && lj == labi[rr]) { A_sum[rr] += logit; c_sum[rr] += 1.f; }
            }
    }

    // plain-sum reduce across the 16 col lanes (low 4 lane bits)
#pragma unroll
    for (int off = 1; off < 16; off <<= 1)
#pragma unroll
        for (int rr = 0; rr < 8; ++rr) {
            s_sum[rr] += __shfl_xor(s_sum[rr], off, 64);
            A_sum[rr] += __shfl_xor(A_sum[rr], off, 64);
            c_sum[rr] += __shfl_xor(c_sum[rr], off, 64);
        }

    if (col16 == 0) {
#pragma unroll
        for (int rr = 0; rr < 8; ++rr)
            stats[ig[rr] * 16 + jc] =
                make_float4(s_sum[rr], A_sum[rr], c_sum[rr], 0.f);
    }
}

// -------- Finalize: sum 16 chunk partials per row, atomic global reduce ----
// Fixed-max semantics: lse = 10 + log(sum exp(l-10)). 16 blocks = 48 atomics.
__global__ __launch_bounds__(256) void finalize_kernel(
    const float4* __restrict__ stats, const int* __restrict__ labels,
    float* __restrict__ accums, float* __restrict__ out) {
    const int tid = threadIdx.x;
    const int r = blockIdx.x * 256 + tid;

    float ssum = 0.f, A = 0.f, cnt = 0.f;
#pragma unroll
    for (int c = 0; c < 16; ++c) {
        float4 v = stats[r * 16 + c];
        ssum += v.x; A += v.y; cnt += v.z;
    }
    float mlpp = 0.f, val = 0.f, nbv = 0.f;
    if (cnt > 0.5f) {   // integer count; > EPS <=> >= 1
        float lse = 10.f + __logf(ssum);
        mlpp = (A - cnt * lse) / (cnt + 1e-8f);
        val = 1.f;
        nbv = (labels[r] != 0) ? 1.f : 0.f;
    }

    __shared__ float red0[256], red1[256], red2[256];
    red0[tid] = mlpp; red1[tid] = val; red2[tid] = nbv;
    __syncthreads();
    for (int off = 128; off > 0; off >>= 1) {
        if (tid < off) {
            red0[tid] += red0[tid + off];
            red1[tid] += red1[tid + off];
            red2[tid] += red2[tid + off];
        }
        __syncthreads();
    }

    if (tid == 0) {
        atomicAdd(&accums[0], red0[0]);
        atomicAdd(&accums[1], red1[0]);
        atomicAdd(&accums[2], red2[0]);
        __threadfence();
        unsigned int old = atomicAdd((unsigned int*)&accums[3], 1u);
        if (old == 15u) {
            float S = atomicAdd(&accums[0], 0.f);
            float V = atomicAdd(&accums[1], 0.f);
            float NB = atomicAdd(&accums[2], 0.f);
            float loss = -S / V;
            out[0] = loss * NB / (NB + 1e-8f);
        }
    }
}

extern "C" void kernel_launch(void* const* d_in, const int* in_sizes, int n_in,
                              void* d_out, int out_size, void* d_ws, size_t ws_size,
                              hipStream_t stream) {
    const float* s = (const float*)d_in[0];
    const float* t = (const float*)d_in[1];
    const int* labels = (const int*)d_in[2];
    float* out = (float*)d_out;

    float* accums = (float*)d_ws;                   // 32 B, zeroed by block 0
    float4* stats = (float4*)((char*)d_ws + 32);    // 4096*16 float4 = 1 MB

    hipLaunchKernelGGL(fused_scl_kernel, dim3(512), dim3(256), 0, stream,
                       s, t, labels, stats, accums);
    hipLaunchKernelGGL(finalize_kernel, dim3(16), dim3(256), 0, stream,
                       stats, labels, accums, out);
}